// Round 12
// baseline (411.972 us; speedup 1.0000x reference)
//
#include <hip/hip_runtime.h>

// GraphSAGE 4-layer encoder, N=100000 nodes, d=64, E=1.6M edges.
//   1. CSR build via 2-level bucket sort (packed bdata; N <= 131072).
//      Per-block dtype self-detection (no global detect pass). EPB=4096.
//   2. gemm1 (x f32 -> Pa,Ra via MFMA); 3x fused {pair-gather L -> LDS tile
//      (+global h) -> MFMA gemm L+1}; final pair-gather (L2-norm, f32 out).
// R11->R12: fusion retried with the PROVEN pair-gather (direct rs loads --
// R10's fence-post shfl trick removed; that was the one untested delta).
// Final-layer gather kept as the untouched proven standalone.

#include <hip/hip_bf16.h>

static inline size_t al256(size_t x) { return (x + 255) & ~(size_t)255; }

#define EPB 4096

typedef _Float16 f16x8 __attribute__((ext_vector_type(8)));
typedef _Float16 h2v __attribute__((ext_vector_type(2)));
typedef float f32x4 __attribute__((ext_vector_type(4)));
union HU { unsigned u32; h2v h; };
union Q4 { uint2 u; _Float16 hh[4]; };

// ---- per-block dtype self-detect: sample 64 odd 32-bit words of this
// block's edge range; int64 -> all high words 0. Returns wave-uniform flag.
__device__ inline int blk_detect(const unsigned int* __restrict__ raw, int E, int base) {
  __shared__ int fsh;
  int t = threadIdx.x;
  if (t == 0) fsh = 0;
  __syncthreads();
  if (t < 64) {
    int i = base + t;
    unsigned nz = (i < E) ? raw[2 * (size_t)i + 1] : 0u;
    unsigned long long b = __ballot(nz != 0u);
    if (t == 0 && b) fsh = 1;
  }
  __syncthreads();
  return fsh;
}

__global__ __launch_bounds__(256) void k_bcount(const unsigned int* __restrict__ raw, int E,
                                                int span, int* __restrict__ bucketCount) {
  __shared__ int lh[256];
  int t = threadIdx.x;
  int base = blockIdx.x * EPB;
  int f = blk_detect(raw, E, base);
  lh[t] = 0;
  __syncthreads();
#pragma unroll 4
  for (int k = 0; k < EPB / 256; ++k) {
    int i = base + k * 256 + t;
    if (i < E) {
      int dst = f ? (int)raw[E + i] : (int)raw[2 * (size_t)(E + i)];
      atomicAdd(&lh[dst / span], 1);
    }
  }
  __syncthreads();
  int c = lh[t];
  if (c) atomicAdd(&bucketCount[t], c);
}

__global__ void k_bscan(const int* __restrict__ bucketCount, int* __restrict__ boff,
                        int* __restrict__ cursorB, int* __restrict__ rs, int N, int E) {
  __shared__ int sa[256], sb[256];
  int t = threadIdx.x;
  int v = bucketCount[t];
  sa[t] = v;
  __syncthreads();
  int* s = sa;
  int* d = sb;
  for (int off = 1; off < 256; off <<= 1) {
    d[t] = s[t] + (t >= off ? s[t - off] : 0);
    __syncthreads();
    int* tmp = s; s = d; d = tmp;
  }
  int inc = s[t];
  int ex = inc - v;
  boff[t] = ex;
  cursorB[t] = ex;
  if (t == 255) boff[256] = inc;
  if (t == 0) rs[N] = E;
}

__global__ __launch_bounds__(256) void k_bscatter(const unsigned int* __restrict__ raw, int E,
                                                  int span, int* __restrict__ cursorB,
                                                  unsigned* __restrict__ bdata) {
  __shared__ int lh[256], lcur[256], gbase[256];
  int t = threadIdx.x;
  int base = blockIdx.x * EPB;
  int f = blk_detect(raw, E, base);
  lh[t] = 0;
  lcur[t] = 0;
  __syncthreads();
#pragma unroll 4
  for (int k = 0; k < EPB / 256; ++k) {
    int i = base + k * 256 + t;
    if (i < E) {
      int dst = f ? (int)raw[E + i] : (int)raw[2 * (size_t)(E + i)];
      atomicAdd(&lh[dst / span], 1);
    }
  }
  __syncthreads();
  int c = lh[t];
  gbase[t] = c ? atomicAdd(&cursorB[t], c) : 0;
  __syncthreads();
#pragma unroll 4
  for (int k = 0; k < EPB / 256; ++k) {
    int i = base + k * 256 + t;
    if (i < E) {
      int s_, d_;
      if (f) { s_ = (int)raw[i]; d_ = (int)raw[E + i]; }
      else   { s_ = (int)raw[2 * (size_t)i]; d_ = (int)raw[2 * (size_t)(E + i)]; }
      int b = d_ / span;
      int pos = atomicAdd(&lcur[b], 1);
      bdata[(size_t)gbase[b] + pos] = ((unsigned)(d_ - b * span) << 17) | (unsigned)s_;
    }
  }
}

__global__ __launch_bounds__(256) void k_bbuild(const unsigned* __restrict__ bdata,
                                                const int* __restrict__ boff, int span, int N,
                                                int* __restrict__ csr, int* __restrict__ rs,
                                                float* __restrict__ invdeg) {
  __shared__ int cnt[512], sa[512], sb[512], cur[512];
  int b = blockIdx.x;
  int t = threadIdx.x;
  int node0 = b * span;
  int beg = boff[b], end = boff[b + 1];
  cnt[t] = 0;
  cnt[t + 256] = 0;
  __syncthreads();
  for (int i = beg + t; i < end; i += 256) {
    atomicAdd(&cnt[bdata[i] >> 17], 1);
  }
  __syncthreads();
  sa[t] = cnt[t];
  sa[t + 256] = cnt[t + 256];
  __syncthreads();
  int* s = sa;
  int* d = sb;
  for (int off = 1; off < 512; off <<= 1) {
    d[t] = s[t] + (t >= off ? s[t - off] : 0);
    int i2 = t + 256;
    d[i2] = s[i2] + (i2 >= off ? s[i2 - off] : 0);
    __syncthreads();
    int* tmp = s; s = d; d = tmp;
  }
  int ex0 = s[t] - cnt[t];
  int ex1 = s[t + 256] - cnt[t + 256];
  cur[t] = ex0;
  cur[t + 256] = ex1;
  if (t < span) {
    int node = node0 + t;
    if (node < N) {
      rs[node] = beg + ex0;
      invdeg[node] = 1.0f / fmaxf((float)cnt[t], 1.0f);
    }
  }
  int t2 = t + 256;
  if (t2 < span) {
    int node = node0 + t2;
    if (node < N) {
      rs[node] = beg + ex1;
      invdeg[node] = 1.0f / fmaxf((float)cnt[t2], 1.0f);
    }
  }
  __syncthreads();
  for (int i = beg + t; i < end; i += 256) {
    unsigned p = bdata[i];
    int pos = atomicAdd(&cur[p >> 17], 1);
    csr[beg + pos] = (int)(p & 0x1FFFFu);
  }
}

// ---- MFMA GEMM (layer 1): P(f16) = x @ Wl ; R(f16) = x @ Wr + bl.
__global__ __launch_bounds__(256) void k_gemm(
    const float* __restrict__ h, const float* __restrict__ Wl,
    const float* __restrict__ Wr, const float* __restrict__ bl,
    unsigned short* __restrict__ Pf, unsigned short* __restrict__ R16, int n) {
  __shared__ uint4 hAu[512];
  char* hAraw = (char*)hAu;
  int t = threadIdx.x;
  int n0 = blockIdx.x * 64;
  int w = t >> 6;
  int l = t & 63;
  int lo16 = l & 15;
  int g = l >> 4;

#pragma unroll
  for (int c = 0; c < 4; ++c) {
    int idx = t + c * 256;
    int row = idx >> 4;
    int fc = idx & 15;
    int nn = n0 + row;
    uint2 u = make_uint2(0u, 0u);
    if (nn < n) {
      float4 hv = *(const float4*)&h[(size_t)nn * 64 + fc * 4];
      union { _Float16 p[4]; uint2 u; } cv;
      cv.p[0] = (_Float16)hv.x; cv.p[1] = (_Float16)hv.y;
      cv.p[2] = (_Float16)hv.z; cv.p[3] = (_Float16)hv.w;
      u = cv.u;
    }
    int byte = (row * 128 + fc * 8) ^ ((row & 7) << 4);
    *(uint2*)(hAraw + byte) = u;
  }

  const float* Wsel = (w < 2) ? Wl : Wr;
  int colbase = (w & 1) * 32;
  f16x8 bfr[2][2];
#pragma unroll
  for (int nf = 0; nf < 2; ++nf) {
    int j = colbase + nf * 16 + lo16;
#pragma unroll
    for (int kk = 0; kk < 2; ++kk) {
      int k0 = kk * 32 + g * 8;
      f16x8 bb;
#pragma unroll
      for (int s = 0; s < 8; ++s) bb[s] = (_Float16)Wsel[(k0 + s) * 64 + j];
      bfr[nf][kk] = bb;
    }
  }
  __syncthreads();

  f32x4 acc[4][2];
#pragma unroll
  for (int mf = 0; mf < 4; ++mf)
#pragma unroll
    for (int nf = 0; nf < 2; ++nf) acc[mf][nf] = (f32x4){0.f, 0.f, 0.f, 0.f};

#pragma unroll
  for (int mf = 0; mf < 4; ++mf) {
    int row = mf * 16 + lo16;
    int swz = (row & 7) << 4;
    f16x8 av0 = *(const f16x8*)(hAraw + row * 128 + ((g * 16) ^ swz));
    f16x8 av1 = *(const f16x8*)(hAraw + row * 128 + ((64 + g * 16) ^ swz));
#pragma unroll
    for (int nf = 0; nf < 2; ++nf) {
      acc[mf][nf] = __builtin_amdgcn_mfma_f32_16x16x32_f16(av0, bfr[nf][0], acc[mf][nf], 0, 0, 0);
      acc[mf][nf] = __builtin_amdgcn_mfma_f32_16x16x32_f16(av1, bfr[nf][1], acc[mf][nf], 0, 0, 0);
    }
  }

#pragma unroll
  for (int nf = 0; nf < 2; ++nf) {
    int col = colbase + nf * 16 + lo16;
    float bv = (w >= 2) ? bl[col] : 0.f;
#pragma unroll
    for (int mf = 0; mf < 4; ++mf) {
#pragma unroll
      for (int r = 0; r < 4; ++r) {
        int grow = n0 + mf * 16 + g * 4 + r;
        if (grow < n) {
          float v = acc[mf][nf][r];
          union { _Float16 hh; unsigned short us; } cv;
          if (w < 2) {
            cv.hh = (_Float16)v;
            Pf[(size_t)grow * 64 + col] = cv.us;
          } else {
            cv.hh = (_Float16)(v + bv);
            R16[(size_t)grow * 64 + col] = cv.us;
          }
        }
      }
    }
  }
}

// ---- FUSED: pair-gather layer L (PROVEN logic, direct rs loads) -> LDS
// tile (+ optional global h16) -> MFMA gemm layer L+1.
// Block = 64 nodes; wave w owns rows w*16..w*16+15 as 8 pairs.
// MODE 0: relu; 1: relu+residual. WRITEH: also store h to global.
template <int MODE, int WRITEH>
__global__ __launch_bounds__(256) void k_fused(
    const uint2* __restrict__ P2, const unsigned short* __restrict__ R16,
    const unsigned short* __restrict__ hres, const int* __restrict__ csr,
    const int* __restrict__ rs, const float* __restrict__ invdeg,
    unsigned short* __restrict__ h16out,
    const float* __restrict__ Wl, const float* __restrict__ Wr,
    const float* __restrict__ bl,
    unsigned short* __restrict__ Pf, unsigned short* __restrict__ R16o,
    int n, int E) {
  __shared__ uint4 hAu[512];
  char* hAraw = (char*)hAu;
  int t = threadIdx.x;
  int w = t >> 6;
  int l = t & 63;
  int lo16 = l & 15;
  int g = l >> 4;
  int n0 = blockIdx.x * 64;
  int half = l >> 5;
  int q = l & 15;
  int g2 = (l >> 4) & 1;

  // B-frags early; latency hides under the gather phase.
  const float* Wsel = (w < 2) ? Wl : Wr;
  int colbase = (w & 1) * 32;
  f16x8 bfr[2][2];
#pragma unroll
  for (int nf = 0; nf < 2; ++nf) {
    int j = colbase + nf * 16 + lo16;
#pragma unroll
    for (int kk = 0; kk < 2; ++kk) {
      int k0 = kk * 32 + g * 8;
      f16x8 bb;
#pragma unroll
      for (int s = 0; s < 8; ++s) bb[s] = (_Float16)Wsel[(k0 + s) * 64 + j];
      bfr[nf][kk] = bb;
    }
  }

  // ---- gather phase: 8 pairs, logic identical to proven k_gatherP.
  for (int p = 0; p < 8; ++p) {
    int row = w * 16 + 2 * p + half;
    int v = n0 + row;
    int bH = rs[v < n ? v : n];
    int eH = rs[(v + 1) < n ? (v + 1) : n];
    int rH = eH - bH;
    float idg = 1.f;
    Q4 rq; rq.u = make_uint2(0u, 0u);
    Q4 hq; hq.u = make_uint2(0u, 0u);
    if ((l & 16) == 0 && v < n) {
      idg = invdeg[v];
      rq.u = *(const uint2*)((const char*)R16 + (size_t)v * 128 + q * 8);
      if (MODE == 1) hq.u = *(const uint2*)((const char*)hres + (size_t)v * 128 + q * 8);
    }
    float s0 = 0.f, s1 = 0.f, s2 = 0.f, s3 = 0.f;
    int rOther = __shfl_xor(rH, 32, 64);
    int maxR = rH > rOther ? rH : rOther;
    int nb = (maxR + 15) >> 4;
    for (int bt = 0; bt < nb; ++bt) {
      int rem = rH - (bt << 4);
      int offc = (rem > 0) ? ((q < rem) ? q : rem - 1) : 0;
      int addr = bH + (bt << 4) + offc;
      addr = (addr < E) ? addr : E - 1;
      int myidx = csr[addr];
      h2v a0 = (h2v)0, a1 = (h2v)0;
      int remMax = maxR - (bt << 4);
#pragma unroll
      for (int tt = 0; tt < 8; ++tt) {
        if (2 * tt >= remMax) break;  // wave-uniform
        int ee = 2 * tt + g2;
        int sel = __shfl(myidx, (half << 5) + ee, 64);
        uint2 u = P2[(unsigned)((sel << 4) + q)];
        bool m = ee < rem;
        HU b0, b1;
        b0.u32 = m ? u.x : 0u;
        b1.u32 = m ? u.y : 0u;
        a0 += b0.h;
        a1 += b1.h;
      }
      s0 += (float)a0[0];
      s1 += (float)a0[1];
      s2 += (float)a1[0];
      s3 += (float)a1[1];
    }
    s0 += __shfl_xor(s0, 16, 64);
    s1 += __shfl_xor(s1, 16, 64);
    s2 += __shfl_xor(s2, 16, 64);
    s3 += __shfl_xor(s3, 16, 64);

    if ((l & 16) == 0) {
      Q4 oq;
      oq.u = make_uint2(0u, 0u);
      if (v < n) {
        float4 o;
        o.x = s0 * idg + (float)rq.hh[0];
        o.y = s1 * idg + (float)rq.hh[1];
        o.z = s2 * idg + (float)rq.hh[2];
        o.w = s3 * idg + (float)rq.hh[3];
        o.x = fmaxf(o.x, 0.f); o.y = fmaxf(o.y, 0.f);
        o.z = fmaxf(o.z, 0.f); o.w = fmaxf(o.w, 0.f);
        if (MODE == 1) {
          o.x += (float)hq.hh[0]; o.y += (float)hq.hh[1];
          o.z += (float)hq.hh[2]; o.w += (float)hq.hh[3];
        }
        oq.hh[0] = (_Float16)o.x; oq.hh[1] = (_Float16)o.y;
        oq.hh[2] = (_Float16)o.z; oq.hh[3] = (_Float16)o.w;
        if (WRITEH)
          *(uint2*)((char*)h16out + (size_t)v * 128 + q * 8) = oq.u;
      }
      int byte = (row * 128 + q * 8) ^ ((row & 7) << 4);
      *(uint2*)(hAraw + byte) = oq.u;  // zeros for v >= n
    }
  }
  __syncthreads();

  // ---- MFMA phase (identical to proven k_gemm body).
  f32x4 acc[4][2];
#pragma unroll
  for (int mf = 0; mf < 4; ++mf)
#pragma unroll
    for (int nf = 0; nf < 2; ++nf) acc[mf][nf] = (f32x4){0.f, 0.f, 0.f, 0.f};

#pragma unroll
  for (int mf = 0; mf < 4; ++mf) {
    int row = mf * 16 + lo16;
    int swz = (row & 7) << 4;
    f16x8 av0 = *(const f16x8*)(hAraw + row * 128 + ((g * 16) ^ swz));
    f16x8 av1 = *(const f16x8*)(hAraw + row * 128 + ((64 + g * 16) ^ swz));
#pragma unroll
    for (int nf = 0; nf < 2; ++nf) {
      acc[mf][nf] = __builtin_amdgcn_mfma_f32_16x16x32_f16(av0, bfr[nf][0], acc[mf][nf], 0, 0, 0);
      acc[mf][nf] = __builtin_amdgcn_mfma_f32_16x16x32_f16(av1, bfr[nf][1], acc[mf][nf], 0, 0, 0);
    }
  }

#pragma unroll
  for (int nf = 0; nf < 2; ++nf) {
    int col = colbase + nf * 16 + lo16;
    float bv = (w >= 2) ? bl[col] : 0.f;
#pragma unroll
    for (int mf = 0; mf < 4; ++mf) {
#pragma unroll
      for (int r = 0; r < 4; ++r) {
        int grow = n0 + mf * 16 + g * 4 + r;
        if (grow < n) {
          float vv = acc[mf][nf][r];
          union { _Float16 hh; unsigned short us; } cv;
          if (w < 2) {
            cv.hh = (_Float16)vv;
            Pf[(size_t)grow * 64 + col] = cv.us;
          } else {
            cv.hh = (_Float16)(vv + bv);
            R16o[(size_t)grow * 64 + col] = cv.us;
          }
        }
      }
    }
  }
}

// ---- standalone PAIR gather (R11-proven, untouched). MODE 2 only here:
// plain + L2-normalize -> f32 out. Block = 8 nodes.
template <int MODE>
__global__ __launch_bounds__(256) void k_gatherP(
    const uint2* __restrict__ P2, const unsigned short* __restrict__ R16,
    const unsigned short* __restrict__ hres, const int* __restrict__ csr,
    const int* __restrict__ rs, const float* __restrict__ invdeg,
    void* __restrict__ hout, int n, int E) {
  int t = threadIdx.x;
  int w = t >> 6;
  int l = t & 63;
  int half = l >> 5;
  int q = l & 15;
  int g2 = (l >> 4) & 1;
  int v = blockIdx.x * 8 + w * 2 + half;
  int bH = rs[v < n ? v : n];
  int eH = rs[(v + 1) < n ? (v + 1) : n];
  int rH = eH - bH;
  float idg = 1.f;
  Q4 rq; rq.u = make_uint2(0u, 0u);
  Q4 hq; hq.u = make_uint2(0u, 0u);
  if ((l & 16) == 0 && v < n) {
    idg = invdeg[v];
    rq.u = *(const uint2*)((const char*)R16 + (size_t)v * 128 + q * 8);
    if (MODE == 1) hq.u = *(const uint2*)((const char*)hres + (size_t)v * 128 + q * 8);
  }
  float s0 = 0.f, s1 = 0.f, s2 = 0.f, s3 = 0.f;
  int rOther = __shfl_xor(rH, 32, 64);
  int maxR = rH > rOther ? rH : rOther;
  int nb = (maxR + 15) >> 4;
  for (int bt = 0; bt < nb; ++bt) {
    int rem = rH - (bt << 4);
    int offc = (rem > 0) ? ((q < rem) ? q : rem - 1) : 0;
    int addr = bH + (bt << 4) + offc;
    addr = (addr < E) ? addr : E - 1;
    int myidx = csr[addr];
    h2v a0 = (h2v)0, a1 = (h2v)0;
    int remMax = maxR - (bt << 4);
#pragma unroll
    for (int tt = 0; tt < 8; ++tt) {
      if (2 * tt >= remMax) break;  // wave-uniform
      int ee = 2 * tt + g2;
      int sel = __shfl(myidx, (half << 5) + ee, 64);
      uint2 u = P2[(unsigned)((sel << 4) + q)];
      bool m = ee < rem;
      HU b0, b1;
      b0.u32 = m ? u.x : 0u;
      b1.u32 = m ? u.y : 0u;
      a0 += b0.h;
      a1 += b1.h;
    }
    s0 += (float)a0[0];
    s1 += (float)a0[1];
    s2 += (float)a1[0];
    s3 += (float)a1[1];
  }
  s0 += __shfl_xor(s0, 16, 64);
  s1 += __shfl_xor(s1, 16, 64);
  s2 += __shfl_xor(s2, 16, 64);
  s3 += __shfl_xor(s3, 16, 64);

  if ((l & 16) == 0 && v < n) {
    float4 o;
    o.x = s0 * idg + (float)rq.hh[0];
    o.y = s1 * idg + (float)rq.hh[1];
    o.z = s2 * idg + (float)rq.hh[2];
    o.w = s3 * idg + (float)rq.hh[3];
    if (MODE == 0) {
      o.x = fmaxf(o.x, 0.f); o.y = fmaxf(o.y, 0.f);
      o.z = fmaxf(o.z, 0.f); o.w = fmaxf(o.w, 0.f);
    } else if (MODE == 1) {
      o.x = fmaxf(o.x, 0.f) + (float)hq.hh[0];
      o.y = fmaxf(o.y, 0.f) + (float)hq.hh[1];
      o.z = fmaxf(o.z, 0.f) + (float)hq.hh[2];
      o.w = fmaxf(o.w, 0.f) + (float)hq.hh[3];
    } else {
      float sq = o.x * o.x + o.y * o.y + o.z * o.z + o.w * o.w;
#pragma unroll
      for (int m = 1; m < 16; m <<= 1) sq += __shfl_xor(sq, m, 64);
      float nrm = fmaxf(sqrtf(sq), 1e-12f);
      o.x /= nrm; o.y /= nrm; o.z /= nrm; o.w /= nrm;
    }
    if (MODE == 2) {
      *(float4*)&((float*)hout)[((size_t)v << 6) + (q << 2)] = o;
    } else {
      Q4 oq;
      oq.hh[0] = (_Float16)o.x; oq.hh[1] = (_Float16)o.y;
      oq.hh[2] = (_Float16)o.z; oq.hh[3] = (_Float16)o.w;
      *(uint2*)((char*)hout + (size_t)v * 128 + q * 8) = oq.u;
    }
  }
}

extern "C" void kernel_launch(void* const* d_in, const int* in_sizes, int n_in,
                              void* d_out, int out_size, void* d_ws, size_t ws_size,
                              hipStream_t stream) {
  const float* x = (const float*)d_in[0];
  const unsigned int* eraw = (const unsigned int*)d_in[1];
  const float* Wl[4] = {(const float*)d_in[2], (const float*)d_in[5],
                        (const float*)d_in[8], (const float*)d_in[11]};
  const float* blv[4] = {(const float*)d_in[3], (const float*)d_in[6],
                         (const float*)d_in[9], (const float*)d_in[12]};
  const float* Wr[4] = {(const float*)d_in[4], (const float*)d_in[7],
                        (const float*)d_in[10], (const float*)d_in[13]};
  const int N = in_sizes[0] / 64;
  const int E = in_sizes[1] / 2;
  const int span = (N + 255) / 256;  // <= 512
  float* out = (float*)d_out;

  char* w = (char*)d_ws;
  size_t off = 0;
  int* bucketCount = (int*)(w + off); off = al256(off + 256 * 4);
  int* boff = (int*)(w + off);        off = al256(off + 257 * 4);
  int* cursorB = (int*)(w + off);     off = al256(off + 256 * 4);
  int* csr = (int*)(w + off);         off = al256(off + (size_t)E * 4);
  float* invdeg = (float*)(w + off);  off = al256(off + (size_t)N * 4);
  int* rs = (int*)(w + off);          off = al256(off + (size_t)(N + 1) * 4);
  unsigned* bdata = (unsigned*)(w + off); off = al256(off + (size_t)E * 4);
  unsigned short* hA = (unsigned short*)(w + off); off = al256(off + (size_t)N * 64 * 2);
  unsigned short* hB = (unsigned short*)(w + off); off = al256(off + (size_t)N * 64 * 2);
  unsigned short* Pa = (unsigned short*)(w + off); off = al256(off + (size_t)N * 64 * 2);
  unsigned short* Ra = (unsigned short*)(w + off); off = al256(off + (size_t)N * 64 * 2);
  unsigned short* Pb = (unsigned short*)(w + off); off = al256(off + (size_t)N * 64 * 2);
  unsigned short* Rb = (unsigned short*)(w + off); off = al256(off + (size_t)N * 64 * 2);

  hipMemsetAsync(bucketCount, 0, 256 * 4, stream);

  int eb = (E + EPB - 1) / EPB;
  k_bcount<<<eb, 256, 0, stream>>>(eraw, E, span, bucketCount);
  k_bscan<<<1, 256, 0, stream>>>(bucketCount, boff, cursorB, rs, N, E);
  k_bscatter<<<eb, 256, 0, stream>>>(eraw, E, span, cursorB, bdata);
  k_bbuild<<<256, 256, 0, stream>>>(bdata, boff, span, N, csr, rs, invdeg);

  int gb = (N + 63) / 64;
  int nb8 = (N + 7) / 8;
  // L1 GEMM: x -> Pa,Ra
  k_gemm<<<gb, 256, 0, stream>>>(x, Wl[0], Wr[0], blv[0], Pa, Ra, N);
  // F1: gather1(Pa,Ra) -> h1 (LDS + hA); gemm2 -> Pb,Rb
  k_fused<0, 1><<<gb, 256, 0, stream>>>((const uint2*)Pa, Ra, nullptr, csr, rs, invdeg,
                                        hA, Wl[1], Wr[1], blv[1], Pb, Rb, N, E);
  // F2: gather2(Pb,Rb,res hA) -> h2 (LDS + hB); gemm3 -> Pa,Ra
  k_fused<1, 1><<<gb, 256, 0, stream>>>((const uint2*)Pb, Rb, hA, csr, rs, invdeg,
                                        hB, Wl[2], Wr[2], blv[2], Pa, Ra, N, E);
  // F3: gather3(Pa,Ra,res hB) -> h3 (LDS only); gemm4 -> Pb,Rb
  k_fused<1, 0><<<gb, 256, 0, stream>>>((const uint2*)Pa, Ra, hB, csr, rs, invdeg,
                                        nullptr, Wl[3], Wr[3], blv[3], Pb, Rb, N, E);
  // final: layer-4 pair-gather + L2 norm -> out (f32)
  k_gatherP<2><<<nb8, 256, 0, stream>>>((const uint2*)Pb, Rb, nullptr, csr, rs, invdeg,
                                        out, N, E);
}

// Round 15
// 291.373 us; speedup vs baseline: 1.4139x; 1.4139x over previous
//
#include <hip/hip_runtime.h>

// GraphSAGE 4-layer encoder, N=100000 nodes, d=64, E=1.6M edges.
//   1. CSR build: fixed-capacity bucket sort (CAP=16384/bucket, 256 buckets,
//      bucket = dst/span). No count/scan passes: bscatter reserves space via
//      cursorB atomics; bbuild derives counts from cursorB. begdeg[v] packs
//      (beg,deg). Per-block dtype self-detect. N <= 131072.
//   2. Per layer: MFMA GEMM (f16 in, f32 acc) -> P, R(f16); pair-gather.
//      P fp8 layers 1-2, f16 layers 3-4 (hybrid precision).
// R14->R15: crash fix. Fixed-capacity csr leaves poison between count and
// CAP; a rem<=0 pair-half loaded csr poison -> negative sel -> OOB P read.
// Fix: myidx = (rem>0) ? myidx : 0 (addresses must be valid even when the
// VALUE is masked -- harness poisons d_ws, garbage is guaranteed).

#include <hip/hip_bf16.h>

static inline size_t al256(size_t x) { return (x + 255) & ~(size_t)255; }

#define EPB 4096
#define CAP 16384  // edges per bucket capacity (mean 6250 for E=1.6M)

typedef _Float16 f16x8 __attribute__((ext_vector_type(8)));
typedef _Float16 h2v __attribute__((ext_vector_type(2)));
typedef float f32x4 __attribute__((ext_vector_type(4)));
typedef float f32x2 __attribute__((ext_vector_type(2)));
union HU { unsigned u32; h2v h; };
union Q4 { uint2 u; _Float16 hh[4]; };

#if defined(__has_builtin)
#if __has_builtin(__builtin_amdgcn_cvt_pk_f32_fp8) && __has_builtin(__builtin_amdgcn_cvt_pk_fp8_f32)
#define FP8_HW 1
#endif
#endif

__device__ inline unsigned char f32_to_fp8(float v) {
#ifdef FP8_HW
  int pk = __builtin_amdgcn_cvt_pk_fp8_f32(v, v, 0, false);
  return (unsigned char)(pk & 0xff);
#else
  union { _Float16 f; unsigned short u; } cv;
  cv.f = (_Float16)v;
  unsigned short h = cv.u;
  unsigned s = (h >> 15) & 1u;
  unsigned e = (h >> 10) & 0x1fu;
  unsigned m = h & 0x3ffu;
  if (e < 9u) return (unsigned char)(s << 7);  // FTZ below 2^-6
  unsigned keep = m >> 7;
  unsigned rnd = (m >> 6) & 1u;
  unsigned sticky = (m & 0x3fu) ? 1u : 0u;
  unsigned inc = rnd & (sticky | (keep & 1u));
  unsigned body = (((e - 8u) << 3) | keep) + inc;
  if (body > 0x7eu) body = 0x7eu;  // clamp, never NaN
  return (unsigned char)((s << 7) | body);
#endif
}

#ifndef FP8_HW
__device__ inline float fp8_to_f32(unsigned b) {
  unsigned m7 = b & 0x7fu;
  union { unsigned short u; _Float16 f; } cv;
  cv.u = (unsigned short)(((b & 0x80u) << 8) | (m7 ? ((m7 << 7) + 0x2000u) : 0u));
  return (float)cv.f;
}
#endif

__device__ inline void fp8x4_acc(unsigned u, float& s0, float& s1, float& s2, float& s3) {
#ifdef FP8_HW
  f32x2 lo = __builtin_amdgcn_cvt_pk_f32_fp8((int)u, false);
  f32x2 hi = __builtin_amdgcn_cvt_pk_f32_fp8((int)u, true);
  s0 += lo[0]; s1 += lo[1]; s2 += hi[0]; s3 += hi[1];
#else
  s0 += fp8_to_f32(u & 0xffu);
  s1 += fp8_to_f32((u >> 8) & 0xffu);
  s2 += fp8_to_f32((u >> 16) & 0xffu);
  s3 += fp8_to_f32(u >> 24);
#endif
}

// ---- per-block dtype self-detect (proven).
__device__ inline int blk_detect(const unsigned int* __restrict__ raw, int E, int base) {
  __shared__ int fsh;
  int t = threadIdx.x;
  if (t == 0) fsh = 0;
  __syncthreads();
  if (t < 64) {
    int i = base + t;
    unsigned nz = (i < E) ? raw[2 * (size_t)i + 1] : 0u;
    unsigned long long b = __ballot(nz != 0u);
    if (t == 0 && b) fsh = 1;
  }
  __syncthreads();
  return fsh;
}

// ---- scatter packed (dstoff<<17 | src) into fixed-capacity bucket regions.
__global__ __launch_bounds__(256) void k_bscatter(const unsigned int* __restrict__ raw, int E,
                                                  int span, int* __restrict__ cursorB,
                                                  unsigned* __restrict__ bdata) {
  __shared__ int lh[256], lcur[256], gbase[256];
  int t = threadIdx.x;
  int base = blockIdx.x * EPB;
  int f = blk_detect(raw, E, base);
  lh[t] = 0;
  lcur[t] = 0;
  __syncthreads();
#pragma unroll 4
  for (int k = 0; k < EPB / 256; ++k) {
    int i = base + k * 256 + t;
    if (i < E) {
      int dst = f ? (int)raw[E + i] : (int)raw[2 * (size_t)(E + i)];
      atomicAdd(&lh[dst / span], 1);
    }
  }
  __syncthreads();
  int c = lh[t];
  gbase[t] = t * CAP + (c ? atomicAdd(&cursorB[t], c) : 0);
  __syncthreads();
#pragma unroll 4
  for (int k = 0; k < EPB / 256; ++k) {
    int i = base + k * 256 + t;
    if (i < E) {
      int s_, d_;
      if (f) { s_ = (int)raw[i]; d_ = (int)raw[E + i]; }
      else   { s_ = (int)raw[2 * (size_t)i]; d_ = (int)raw[2 * (size_t)(E + i)]; }
      int b = d_ / span;
      int pos = atomicAdd(&lcur[b], 1);
      bdata[(size_t)gbase[b] + pos] = ((unsigned)(d_ - b * span) << 17) | (unsigned)s_;
    }
  }
}

// ---- one block per bucket: node histogram + scan in LDS, write begdeg
// (beg,deg) and scatter src ids into csr[b*CAP ..]. span <= 512.
__global__ __launch_bounds__(256) void k_bbuild(const unsigned* __restrict__ bdata,
                                                const int* __restrict__ cursorB, int span, int N,
                                                int* __restrict__ csr, int2* __restrict__ begdeg) {
  __shared__ int cnt[512], sa[512], sb[512], cur[512];
  int b = blockIdx.x;
  int t = threadIdx.x;
  int node0 = b * span;
  int beg = b * CAP;
  int end = beg + cursorB[b];
  cnt[t] = 0;
  cnt[t + 256] = 0;
  __syncthreads();
  for (int i = beg + t; i < end; i += 256) {
    atomicAdd(&cnt[bdata[i] >> 17], 1);
  }
  __syncthreads();
  sa[t] = cnt[t];
  sa[t + 256] = cnt[t + 256];
  __syncthreads();
  int* s = sa;
  int* d = sb;
  for (int off = 1; off < 512; off <<= 1) {
    d[t] = s[t] + (t >= off ? s[t - off] : 0);
    int i2 = t + 256;
    d[i2] = s[i2] + (i2 >= off ? s[i2 - off] : 0);
    __syncthreads();
    int* tmp = s; s = d; d = tmp;
  }
  int ex0 = s[t] - cnt[t];
  int ex1 = s[t + 256] - cnt[t + 256];
  cur[t] = ex0;
  cur[t + 256] = ex1;
  if (t < span) {
    int node = node0 + t;
    if (node < N) begdeg[node] = make_int2(beg + ex0, cnt[t]);
  }
  int t2 = t + 256;
  if (t2 < span) {
    int node = node0 + t2;
    if (node < N) begdeg[node] = make_int2(beg + ex1, cnt[t2]);
  }
  __syncthreads();
  for (int i = beg + t; i < end; i += 256) {
    unsigned p = bdata[i];
    int pos = atomicAdd(&cur[p >> 17], 1);
    csr[beg + pos] = (int)(p & 0x1FFFFu);
  }
}

// ---- MFMA GEMM: P = h @ Wl (fp8 if P8 else f16); R(f16) = h @ Wr + bl.
// IT=0: h f32; IT=1: h f16. (proven body; only P store dtype templated)
template <int IT, int P8>
__global__ __launch_bounds__(256) void k_gemm(
    const void* __restrict__ hv_, const float* __restrict__ Wl,
    const float* __restrict__ Wr, const float* __restrict__ bl,
    void* __restrict__ Pv, unsigned short* __restrict__ R16, int n) {
  __shared__ uint4 hAu[512];
  char* hAraw = (char*)hAu;
  int t = threadIdx.x;
  int n0 = blockIdx.x * 64;
  int w = t >> 6;
  int l = t & 63;
  int lo16 = l & 15;
  int g = l >> 4;

#pragma unroll
  for (int c = 0; c < 4; ++c) {
    int idx = t + c * 256;
    int row = idx >> 4;
    int fc = idx & 15;
    int nn = n0 + row;
    uint2 u = make_uint2(0u, 0u);
    if (nn < n) {
      if (IT == 0) {
        const float* h = (const float*)hv_;
        float4 hv = *(const float4*)&h[(size_t)nn * 64 + fc * 4];
        union { _Float16 p[4]; uint2 u; } cv;
        cv.p[0] = (_Float16)hv.x; cv.p[1] = (_Float16)hv.y;
        cv.p[2] = (_Float16)hv.z; cv.p[3] = (_Float16)hv.w;
        u = cv.u;
      } else {
        u = *(const uint2*)((const char*)hv_ + (size_t)nn * 128 + fc * 8);
      }
    }
    int byte = (row * 128 + fc * 8) ^ ((row & 7) << 4);
    *(uint2*)(hAraw + byte) = u;
  }

  const float* Wsel = (w < 2) ? Wl : Wr;
  int colbase = (w & 1) * 32;
  f16x8 bfr[2][2];
#pragma unroll
  for (int nf = 0; nf < 2; ++nf) {
    int j = colbase + nf * 16 + lo16;
#pragma unroll
    for (int kk = 0; kk < 2; ++kk) {
      int k0 = kk * 32 + g * 8;
      f16x8 bb;
#pragma unroll
      for (int s = 0; s < 8; ++s) bb[s] = (_Float16)Wsel[(k0 + s) * 64 + j];
      bfr[nf][kk] = bb;
    }
  }
  __syncthreads();

  f32x4 acc[4][2];
#pragma unroll
  for (int mf = 0; mf < 4; ++mf)
#pragma unroll
    for (int nf = 0; nf < 2; ++nf) acc[mf][nf] = (f32x4){0.f, 0.f, 0.f, 0.f};

#pragma unroll
  for (int mf = 0; mf < 4; ++mf) {
    int row = mf * 16 + lo16;
    int swz = (row & 7) << 4;
    f16x8 av0 = *(const f16x8*)(hAraw + row * 128 + ((g * 16) ^ swz));
    f16x8 av1 = *(const f16x8*)(hAraw + row * 128 + ((64 + g * 16) ^ swz));
#pragma unroll
    for (int nf = 0; nf < 2; ++nf) {
      acc[mf][nf] = __builtin_amdgcn_mfma_f32_16x16x32_f16(av0, bfr[nf][0], acc[mf][nf], 0, 0, 0);
      acc[mf][nf] = __builtin_amdgcn_mfma_f32_16x16x32_f16(av1, bfr[nf][1], acc[mf][nf], 0, 0, 0);
    }
  }

#pragma unroll
  for (int nf = 0; nf < 2; ++nf) {
    int col = colbase + nf * 16 + lo16;
    float bv = (w >= 2) ? bl[col] : 0.f;
#pragma unroll
    for (int mf = 0; mf < 4; ++mf) {
#pragma unroll
      for (int r = 0; r < 4; ++r) {
        int grow = n0 + mf * 16 + g * 4 + r;
        if (grow < n) {
          float v = acc[mf][nf][r];
          if (w < 2) {
            if (P8) {
              ((unsigned char*)Pv)[(size_t)grow * 64 + col] = f32_to_fp8(v);
            } else {
              union { _Float16 hh; unsigned short us; } cv;
              cv.hh = (_Float16)v;
              ((unsigned short*)Pv)[(size_t)grow * 64 + col] = cv.us;
            }
          } else {
            union { _Float16 hh; unsigned short us; } cv;
            cv.hh = (_Float16)(v + bv);
            R16[(size_t)grow * 64 + col] = cv.us;
          }
        }
      }
    }
  }
}

// ---- pair gather (proven structure). P8=1: fp8 rows (64B); P8=0: f16 rows
// (128B). Lane l: half=l>>5 node, q=l&15 dim-quad, g2=(l>>4)&1 edge parity.
// MODE 0 relu->f16; 1 relu+res->f16; 2 plain+L2norm->f32.
// CRITICAL: myidx forced to 0 when rem<=0 -- csr beyond each bucket's count
// is poison, and a poisoned index is an OOB ADDRESS even if value-masked.
template <int MODE, int P8>
__global__ __launch_bounds__(256) void k_gatherP(
    const void* __restrict__ Pv, const unsigned short* __restrict__ R16,
    const unsigned short* __restrict__ hres, const int* __restrict__ csr,
    const int2* __restrict__ begdeg, void* __restrict__ hout, int n, int limit) {
  int t = threadIdx.x;
  int w = t >> 6;
  int l = t & 63;
  int half = l >> 5;
  int q = l & 15;
  int g2 = (l >> 4) & 1;
  int v = blockIdx.x * 8 + w * 2 + half;
  int bH = 0, rH = 0;
  if (v < n) {
    int2 bd = begdeg[v];
    bH = bd.x;
    rH = bd.y;
  }
  float idg = 1.0f / fmaxf((float)rH, 1.0f);
  Q4 rq; rq.u = make_uint2(0u, 0u);
  Q4 hq; hq.u = make_uint2(0u, 0u);
  if ((l & 16) == 0 && v < n) {
    rq.u = *(const uint2*)((const char*)R16 + (size_t)v * 128 + q * 8);
    if (MODE == 1) hq.u = *(const uint2*)((const char*)hres + (size_t)v * 128 + q * 8);
  }
  float s0 = 0.f, s1 = 0.f, s2 = 0.f, s3 = 0.f;
  int rOther = __shfl_xor(rH, 32, 64);
  int maxR = rH > rOther ? rH : rOther;
  int nb = (maxR + 15) >> 4;
  for (int bt = 0; bt < nb; ++bt) {
    int rem = rH - (bt << 4);
    int offc = (rem > 0) ? ((q < rem) ? q : rem - 1) : 0;
    int addr = bH + (bt << 4) + offc;
    addr = (addr < limit) ? addr : limit - 1;
    int myidx = csr[addr];
    myidx = (rem > 0) ? myidx : 0;  // poison-proof: index 0 always valid
    int remMax = maxR - (bt << 4);
    if (P8) {
#pragma unroll
      for (int tt = 0; tt < 8; ++tt) {
        if (2 * tt >= remMax) break;  // wave-uniform
        int ee = 2 * tt + g2;
        int sel = __shfl(myidx, (half << 5) + ee, 64);
        unsigned u = ((const unsigned*)Pv)[(unsigned)((sel << 4) + q)];
        u = (ee < rem) ? u : 0u;  // fp8 0x00 == 0.0
        fp8x4_acc(u, s0, s1, s2, s3);
      }
    } else {
      h2v a0 = (h2v)0, a1 = (h2v)0;
#pragma unroll
      for (int tt = 0; tt < 8; ++tt) {
        if (2 * tt >= remMax) break;  // wave-uniform
        int ee = 2 * tt + g2;
        int sel = __shfl(myidx, (half << 5) + ee, 64);
        uint2 u = ((const uint2*)Pv)[(unsigned)((sel << 4) + q)];
        bool m = ee < rem;
        HU b0, b1;
        b0.u32 = m ? u.x : 0u;
        b1.u32 = m ? u.y : 0u;
        a0 += b0.h;
        a1 += b1.h;
      }
      s0 += (float)a0[0];
      s1 += (float)a0[1];
      s2 += (float)a1[0];
      s3 += (float)a1[1];
    }
  }
  s0 += __shfl_xor(s0, 16, 64);
  s1 += __shfl_xor(s1, 16, 64);
  s2 += __shfl_xor(s2, 16, 64);
  s3 += __shfl_xor(s3, 16, 64);

  if ((l & 16) == 0 && v < n) {
    float4 o;
    o.x = s0 * idg + (float)rq.hh[0];
    o.y = s1 * idg + (float)rq.hh[1];
    o.z = s2 * idg + (float)rq.hh[2];
    o.w = s3 * idg + (float)rq.hh[3];
    if (MODE == 0) {
      o.x = fmaxf(o.x, 0.f); o.y = fmaxf(o.y, 0.f);
      o.z = fmaxf(o.z, 0.f); o.w = fmaxf(o.w, 0.f);
    } else if (MODE == 1) {
      o.x = fmaxf(o.x, 0.f) + (float)hq.hh[0];
      o.y = fmaxf(o.y, 0.f) + (float)hq.hh[1];
      o.z = fmaxf(o.z, 0.f) + (float)hq.hh[2];
      o.w = fmaxf(o.w, 0.f) + (float)hq.hh[3];
    } else {
      float sq = o.x * o.x + o.y * o.y + o.z * o.z + o.w * o.w;
#pragma unroll
      for (int m = 1; m < 16; m <<= 1) sq += __shfl_xor(sq, m, 64);
      float nrm = fmaxf(sqrtf(sq), 1e-12f);
      o.x /= nrm; o.y /= nrm; o.z /= nrm; o.w /= nrm;
    }
    if (MODE == 2) {
      *(float4*)&((float*)hout)[((size_t)v << 6) + (q << 2)] = o;
    } else {
      Q4 oq;
      oq.hh[0] = (_Float16)o.x; oq.hh[1] = (_Float16)o.y;
      oq.hh[2] = (_Float16)o.z; oq.hh[3] = (_Float16)o.w;
      *(uint2*)((char*)hout + (size_t)v * 128 + q * 8) = oq.u;
    }
  }
}

extern "C" void kernel_launch(void* const* d_in, const int* in_sizes, int n_in,
                              void* d_out, int out_size, void* d_ws, size_t ws_size,
                              hipStream_t stream) {
  const float* x = (const float*)d_in[0];
  const unsigned int* eraw = (const unsigned int*)d_in[1];
  const float* Wl[4] = {(const float*)d_in[2], (const float*)d_in[5],
                        (const float*)d_in[8], (const float*)d_in[11]};
  const float* blv[4] = {(const float*)d_in[3], (const float*)d_in[6],
                         (const float*)d_in[9], (const float*)d_in[12]};
  const float* Wr[4] = {(const float*)d_in[4], (const float*)d_in[7],
                        (const float*)d_in[10], (const float*)d_in[13]};
  const int N = in_sizes[0] / 64;
  const int E = in_sizes[1] / 2;
  const int span = (N + 255) / 256;  // <= 512
  const int limit = 256 * CAP;
  float* out = (float*)d_out;

  char* w = (char*)d_ws;
  size_t off = 0;
  int* cursorB = (int*)(w + off);     off = al256(off + 256 * 4);
  int* csr = (int*)(w + off);         off = al256(off + (size_t)256 * CAP * 4);
  unsigned* bdata = (unsigned*)(w + off); off = al256(off + (size_t)256 * CAP * 4);
  int2* begdeg = (int2*)(w + off);    off = al256(off + (size_t)N * 8);
  unsigned short* hA = (unsigned short*)(w + off); off = al256(off + (size_t)N * 64 * 2);
  unsigned short* hB = (unsigned short*)(w + off); off = al256(off + (size_t)N * 64 * 2);
  unsigned char* Pf8 = (unsigned char*)(w + off);  off = al256(off + (size_t)N * 64);
  unsigned short* Pf16 = (unsigned short*)(w + off); off = al256(off + (size_t)N * 64 * 2);
  unsigned short* R16 = (unsigned short*)(w + off); off = al256(off + (size_t)N * 64 * 2);

  hipMemsetAsync(cursorB, 0, 256 * 4, stream);

  int eb = (E + EPB - 1) / EPB;
  k_bscatter<<<eb, 256, 0, stream>>>(eraw, E, span, cursorB, bdata);
  k_bbuild<<<256, 256, 0, stream>>>(bdata, cursorB, span, N, csr, begdeg);

  int gb = (N + 63) / 64;
  int nb8 = (N + 7) / 8;
  // Layer 1: x(f32) -> hA (relu, f16); P fp8
  k_gemm<0, 1><<<gb, 256, 0, stream>>>(x, Wl[0], Wr[0], blv[0], Pf8, R16, N);
  k_gatherP<0, 1><<<nb8, 256, 0, stream>>>(Pf8, R16, nullptr, csr, begdeg, hA, N, limit);
  // Layer 2: hA -> hB (relu + residual hA, f16); P fp8
  k_gemm<1, 1><<<gb, 256, 0, stream>>>(hA, Wl[1], Wr[1], blv[1], Pf8, R16, N);
  k_gatherP<1, 1><<<nb8, 256, 0, stream>>>(Pf8, R16, hA, csr, begdeg, hB, N, limit);
  // Layer 3: hB -> hA (relu + residual hB, f16); P f16
  k_gemm<1, 0><<<gb, 256, 0, stream>>>(hB, Wl[2], Wr[2], blv[2], Pf16, R16, N);
  k_gatherP<1, 0><<<nb8, 256, 0, stream>>>(Pf16, R16, hB, csr, begdeg, hA, N, limit);
  // Layer 4: hA -> out (no act, L2-normalize rows, f32); P f16
  k_gemm<1, 0><<<gb, 256, 0, stream>>>(hA, Wl[3], Wr[3], blv[3], Pf16, R16, N);
  k_gatherP<2, 0><<<nb8, 256, 0, stream>>>(Pf16, R16, nullptr, csr, begdeg, out, N, limit);
}